// Round 7
// baseline (181.423 us; speedup 1.0000x reference)
//
#include <hip/hip_runtime.h>
#include <hip/hip_bf16.h>

// ROUND 7 = DIAGNOSTIC. R5 kernels (best: 29.3us) + runtime rep loops so each
// kernel's dispatch exceeds the ~40us harness fills and surfaces in top-5
// rocprof rows with its own counters. Work is idempotent per rep -> output
// identical. real_cost ~= dur/rep (reps are cache-warm; delta vs cold = HBM).

#define B_     64
#define M_     127
#define TWOB_  128

using bf16x8 = __attribute__((ext_vector_type(8))) short;
using f32x4  = __attribute__((ext_vector_type(4))) float;

__device__ inline short f2bf(float x) {
    __hip_bfloat16 h = __float2bfloat16(x);
    return *reinterpret_cast<short*>(&h);
}

// ---------------------------------------------------------------------------
// Kernel 1 (R5 build_Em + rep): Em_bf16[m][l][k]
// ---------------------------------------------------------------------------
__global__ __launch_bounds__(256) void build_Em(
    const float* __restrict__ Cm,
    const float* __restrict__ XFc,
    const float* __restrict__ XFs,
    const float* __restrict__ Dval,
    const int*   __restrict__ Drow,
    const int*   __restrict__ Dcol,
    int nnz,
    __hip_bfloat16* __restrict__ Em,
    int rep)
{
    __shared__ float Dm[16 * B_];
    const int m  = blockIdx.y;
    const int l0 = blockIdx.x * 16;
    const int t  = threadIdx.x;

    for (int r = 0; r < rep; ++r) {
        __syncthreads();
        for (int i = t; i < 16 * B_; i += 256) Dm[i] = 0.f;

        int lo, hi;
        {
            int target = m * B_ + l0;
            int a = 0, b = nnz;
            while (a < b) { int mid = (a + b) >> 1; if (Drow[mid] < target) a = mid + 1; else b = mid; }
            lo = a;
            target = m * B_ + l0 + 16;
            b = nnz;
            while (a < b) { int mid = (a + b) >> 1; if (Drow[mid] < target) a = mid + 1; else b = mid; }
            hi = a;
        }
        __syncthreads();
        for (int i = lo + t; i < hi; i += 256) {
            int l = Drow[i] - m * B_ - l0;
            int n = Dcol[i] - m * TWOB_;
            Dm[l * B_ + n] = Dval[i];
        }
        __syncthreads();

        const float* __restrict__ XF = (m & 1) ? XFc : XFs;
        const float cm = Cm[m];
        const int k  = t & 127;
        const int lh = t >> 7;

        const float4* __restrict__ XFrow = reinterpret_cast<const float4*>(XF + k * TWOB_);
        float4 xf[16];
        #pragma unroll
        for (int q = 0; q < 16; ++q) xf[q] = XFrow[q];

        const float4* __restrict__ dmq = reinterpret_cast<const float4*>(Dm) + (lh * 8) * 16;
        float acc[8] = {};
        #pragma unroll
        for (int q = 0; q < 16; ++q) {
            #pragma unroll
            for (int j = 0; j < 8; ++j) {
                float4 dm = dmq[j * 16 + q];
                acc[j] += xf[q].x * dm.x + xf[q].y * dm.y + xf[q].z * dm.z + xf[q].w * dm.w;
            }
        }
        #pragma unroll
        for (int j = 0; j < 8; ++j) {
            int l = l0 + lh * 8 + j;
            Em[(size_t)(m * B_ + l) * TWOB_ + k] = __float2bfloat16(cm * acc[j]);
        }
    }
}

// ---------------------------------------------------------------------------
// Kernel 2 (R5 fdlt_gemm + rep): DMA-staged LDS, MFMA, float4 epilogue.
// ---------------------------------------------------------------------------
__global__ __launch_bounds__(256) void fdlt_gemm(
    const float* __restrict__ psiHat,
    const __hip_bfloat16* __restrict__ Em,
    float* __restrict__ out,
    int rep)
{
    __shared__ float As[64 * 128];
    __shared__ short Es[64 * 128];

    const int bid  = blockIdx.x;
    const int xcd  = bid & 7;
    const int rest = bid >> 3;
    const int m    = xcd + ((rest & 15) << 3);
    const int tile = rest >> 4;
    if (m >= M_) return;
    const int b0 = tile * 64;
    const int t  = threadIdx.x;
    const int wbase = t & 192;

    for (int r = 0; r < rep; ++r) {
        __syncthreads();
        #pragma unroll
        for (int j = 0; j < 8; ++j) {
            int L   = t + j * 256;
            int row = L >> 5;
            int u   = L & 31;
            int us  = u ^ (row & 15);
            const float* src = psiHat + ((size_t)(b0 + row) * M_ + m) * TWOB_ + (us << 2);
            float* dst = As + (size_t)(wbase + j * 256) * 4;
            __builtin_amdgcn_global_load_lds((const uint32_t*)src, (uint32_t*)dst, 16, 0, 0);
        }
        #pragma unroll
        for (int j = 0; j < 4; ++j) {
            int L   = t + j * 256;
            int row = L >> 4;
            int u   = L & 15;
            int us  = u ^ (row & 15);
            const __hip_bfloat16* src = Em + (size_t)m * (B_ * TWOB_) + row * TWOB_ + (us << 3);
            short* dst = Es + (size_t)(wbase + j * 256) * 8;
            __builtin_amdgcn_global_load_lds((const uint32_t*)src, (uint32_t*)dst, 16, 0, 0);
        }
        __syncthreads();

        const int lane = t & 63;
        const int w    = t >> 6;
        const int lr   = lane & 15;
        const int lg   = lane >> 4;

        f32x4 acc[4];
        #pragma unroll
        for (int nt = 0; nt < 4; ++nt) acc[nt] = (f32x4){0.f, 0.f, 0.f, 0.f};

        const short* __restrict__ ebase = Es + (w * 16 + lr) * TWOB_;

        #pragma unroll
        for (int ks = 0; ks < 4; ++ks) {
            int g = ks * 4 + lg;
            bf16x8 af = *reinterpret_cast<const bf16x8*>(ebase + ((g ^ lr) << 3));
            #pragma unroll
            for (int nt = 0; nt < 4; ++nt) {
                int row = nt * 16 + lr;
                int u0  = ks * 8 + lg * 2;
                f32x4 p0 = *reinterpret_cast<const f32x4*>(As + row * TWOB_ + (((u0    ) ^ lr) << 2));
                f32x4 p1 = *reinterpret_cast<const f32x4*>(As + row * TWOB_ + (((u0 + 1) ^ lr) << 2));
                bf16x8 bf;
                bf[0] = f2bf(p0[0]); bf[1] = f2bf(p0[1]); bf[2] = f2bf(p0[2]); bf[3] = f2bf(p0[3]);
                bf[4] = f2bf(p1[0]); bf[5] = f2bf(p1[1]); bf[6] = f2bf(p1[2]); bf[7] = f2bf(p1[3]);
                acc[nt] = __builtin_amdgcn_mfma_f32_16x16x32_bf16(af, bf, acc[nt], 0, 0, 0);
            }
        }

        #pragma unroll
        for (int nt = 0; nt < 4; ++nt) {
            int b = b0 + nt * 16 + lr;
            float4 v;
            v.x = acc[nt][0]; v.y = acc[nt][1]; v.z = acc[nt][2]; v.w = acc[nt][3];
            *reinterpret_cast<float4*>(out + ((size_t)b * M_ + m) * B_ + w * 16 + lg * 4) = v;
        }
    }
}

extern "C" void kernel_launch(void* const* d_in, const int* in_sizes, int n_in,
                              void* d_out, int out_size, void* d_ws, size_t ws_size,
                              hipStream_t stream) {
    const float* psiHat = (const float*)d_in[0];
    const float* Cm     = (const float*)d_in[1];
    const float* XFc    = (const float*)d_in[2];
    const float* XFs    = (const float*)d_in[3];
    const float* Dval   = (const float*)d_in[4];
    const int*   Drow   = (const int*)d_in[5];
    const int*   Dcol   = (const int*)d_in[6];
    const int nnz = in_sizes[4];

    __hip_bfloat16* Em = (__hip_bfloat16*)d_ws;

    build_Em<<<dim3(4, M_), dim3(256), 0, stream>>>(Cm, XFc, XFs, Dval, Drow, Dcol, nnz, Em, 16);
    fdlt_gemm<<<dim3(1024), dim3(256), 0, stream>>>(psiHat, Em, (float*)d_out, 8);
}

// Round 8
// 26.649 us; speedup vs baseline: 6.8077x; 6.8077x over previous
//
#include <hip/hip_runtime.h>
#include <hip/hip_bf16.h>

// FDLT: out[b,m,l] = sum_k psiHat[b,m,k] * Em[m][k][l]   (fp32 in/out)
//   Em[m][k][l] = Cm[m] * sum_{n=0..63} XF_sel(m)[k][n] * Dm[m][l][n]
// B=64, M=127, 2B=128, BATCH=512. Em bf16 [m][l][k] in d_ws.
// Round 8 (from R7 diagnostic: build ~7.9us latency-bound, gemm ~18us):
//  k1 build_Em: MFMA GEMM per m (COO -> LDS bf16 tile, XF frags from L2),
//     replaces 7.9us VALU-latency version; also absorbs dm_dense.
//  k2 fdlt_gemm: Es LDS tile REMOVED (A-frags direct from L2-hot Em) ->
//     LDS 32KB -> 5 blocks/CU for cross-block latency hiding. As staging
//     via global_load_lds (swizzled source, linear dest) as R5.

#define B_     64
#define M_     127
#define TWOB_  128

using bf16x8 = __attribute__((ext_vector_type(8))) short;  // 8 bf16 (4 VGPR)
using f32x4  = __attribute__((ext_vector_type(4))) float;

__device__ inline short f2bf(float x) {
    __hip_bfloat16 h = __float2bfloat16(x);
    return *reinterpret_cast<short*>(&h);
}

// ---------------------------------------------------------------------------
// Kernel 1: per m, Em[64l x 128k] = bf16( cm * Dm[64l x 64n] @ XF[128k x 64n]^T )
// via mfma_f32_16x16x32_bf16. 127 blocks x 256 thr (4 waves).
// LDS: Dmb bf16 [64l][64n], 8KB, 16B-unit swizzle u ^= (l&7)  (frag reads
// stride 128B/row -> unswizzled would be same-bank; swizzled = 2-way, free).
// A-frag = XF rows (k): 8 fp32 direct from global (64KB, L2-hot) + cvt.
// B-frag = Dmb cols (l). MFMA D: col=lane&15 -> l, row=lg*4+r -> k (4
// consecutive k per lane -> 8B packed stores).
// ---------------------------------------------------------------------------
__global__ __launch_bounds__(256) void build_Em(
    const float* __restrict__ Cm,
    const float* __restrict__ XFc,
    const float* __restrict__ XFs,
    const float* __restrict__ Dval,
    const int*   __restrict__ Drow,
    const int*   __restrict__ Dcol,
    int nnz,
    __hip_bfloat16* __restrict__ Em)
{
    __shared__ short Dmb[B_ * B_];   // 8 KB
    const int m = blockIdx.x;
    const int t = threadIdx.x;

    {   // zero 8KB: 512 uint4, 2 per thread
        uint4 z = make_uint4(0, 0, 0, 0);
        uint4* p = reinterpret_cast<uint4*>(Dmb);
        p[t] = z;
        p[t + 256] = z;
    }
    // COO segment for rows [m*64, (m+1)*64)  (rows sorted)
    int lo, hi;
    {
        int target = m * B_;
        int a = 0, b = nnz;
        while (a < b) { int mid = (a + b) >> 1; if (Drow[mid] < target) a = mid + 1; else b = mid; }
        lo = a;
        target = (m + 1) * B_;
        b = nnz;
        while (a < b) { int mid = (a + b) >> 1; if (Drow[mid] < target) a = mid + 1; else b = mid; }
        hi = a;
    }
    __syncthreads();
    for (int i = lo + t; i < hi; i += 256) {
        int l = Drow[i] - m * B_;
        int n = Dcol[i] - m * TWOB_;
        int u = n >> 3;                          // 16B unit within row
        Dmb[l * B_ + (((u ^ (l & 7)) << 3) | (n & 7))] = f2bf(Dval[i]);
    }
    __syncthreads();

    const float* __restrict__ XF = (m & 1) ? XFc : XFs;
    const float cm = Cm[m];
    const int w    = t >> 6;          // wave: k rows [w*32, w*32+32)
    const int lane = t & 63;
    const int lr   = lane & 15;
    const int lg   = lane >> 4;

    f32x4 acc[2][4];
    #pragma unroll
    for (int at = 0; at < 2; ++at)
        #pragma unroll
        for (int nt = 0; nt < 4; ++nt) acc[at][nt] = (f32x4){0.f, 0.f, 0.f, 0.f};

    #pragma unroll
    for (int ks = 0; ks < 2; ++ks) {             // n-halves of 32
        bf16x8 af[2];
        #pragma unroll
        for (int at = 0; at < 2; ++at) {         // A: XF row k = w*32+at*16+lr
            const float* ap = XF + (size_t)(w * 32 + at * 16 + lr) * TWOB_ + ks * 32 + lg * 8;
            f32x4 p0 = *reinterpret_cast<const f32x4*>(ap);
            f32x4 p1 = *reinterpret_cast<const f32x4*>(ap + 4);
            af[at][0] = f2bf(p0[0]); af[at][1] = f2bf(p0[1]);
            af[at][2] = f2bf(p0[2]); af[at][3] = f2bf(p0[3]);
            af[at][4] = f2bf(p1[0]); af[at][5] = f2bf(p1[1]);
            af[at][6] = f2bf(p1[2]); af[at][7] = f2bf(p1[3]);
        }
        #pragma unroll
        for (int nt = 0; nt < 4; ++nt) {         // B: Dmb col l = nt*16+lr
            int l = nt * 16 + lr;
            int g = ks * 4 + lg;
            bf16x8 bf = *reinterpret_cast<const bf16x8*>(Dmb + l * B_ + ((g ^ (l & 7)) << 3));
            #pragma unroll
            for (int at = 0; at < 2; ++at)
                acc[at][nt] = __builtin_amdgcn_mfma_f32_16x16x32_bf16(af[at], bf, acc[at][nt], 0, 0, 0);
        }
    }

    // store: lane holds l = nt*16+lr, k = w*32+at*16+lg*4 .. +3
    #pragma unroll
    for (int at = 0; at < 2; ++at) {
        #pragma unroll
        for (int nt = 0; nt < 4; ++nt) {
            int l  = nt * 16 + lr;
            int k0 = w * 32 + at * 16 + lg * 4;
            unsigned short h0 = (unsigned short)f2bf(cm * acc[at][nt][0]);
            unsigned short h1 = (unsigned short)f2bf(cm * acc[at][nt][1]);
            unsigned short h2 = (unsigned short)f2bf(cm * acc[at][nt][2]);
            unsigned short h3 = (unsigned short)f2bf(cm * acc[at][nt][3]);
            uint2 pack;
            pack.x = (unsigned)h0 | ((unsigned)h1 << 16);
            pack.y = (unsigned)h2 | ((unsigned)h3 << 16);
            *reinterpret_cast<uint2*>(Em + (size_t)(m * B_ + l) * TWOB_ + k0) = pack;
        }
    }
}

// ---------------------------------------------------------------------------
// Kernel 2: per (m, batch-tile): out[64l x 64b] = E[64l x 128k] @ A[128k x 64b]
// 1024 blocks, XCD mapping m = (bid&7) + 8*((bid>>3)&15), tile = bid>>7
//   -> 16 Em matrices (256 KB) per XCD, L2-hot.
// As (psiHat fp32, 32KB) staged via global_load_lds width=16, swizzled SOURCE
// + linear LDS dest (R5). Es tile removed: A-frags (Em rows, bf16x8 = 16B)
// loaded DIRECTLY from global L2. LDS 32KB -> ~5 blocks/CU residency.
// D: col=lane&15=b, row=lg*4+r=l -> float4 store of 4 consecutive l.
// ---------------------------------------------------------------------------
__global__ __launch_bounds__(256) void fdlt_gemm(
    const float* __restrict__ psiHat,
    const __hip_bfloat16* __restrict__ Em,
    float* __restrict__ out)
{
    __shared__ float As[64 * 128];   // fp32 [b][k], 32 KB, unit-swizzled

    const int bid  = blockIdx.x;
    const int xcd  = bid & 7;
    const int rest = bid >> 3;
    const int m    = xcd + ((rest & 15) << 3);
    const int tile = rest >> 4;
    if (m >= M_) return;             // 8 guard blocks, uniform exit (no barrier yet)
    const int b0 = tile * 64;
    const int t  = threadIdx.x;
    const int wbase = t & 192;       // wave id * 64

    // DMA stage As: 2048 16B-units, 8/thread. LDS linear, source unit-swizzled.
    #pragma unroll
    for (int j = 0; j < 8; ++j) {
        int L   = t + j * 256;
        int row = L >> 5;
        int u   = L & 31;
        int us  = u ^ (row & 15);
        const float* src = psiHat + ((size_t)(b0 + row) * M_ + m) * TWOB_ + (us << 2);
        float* dst = As + (size_t)(wbase + j * 256) * 4;
        __builtin_amdgcn_global_load_lds((const uint32_t*)src, (uint32_t*)dst, 16, 0, 0);
    }

    const int lane = t & 63;
    const int w    = t >> 6;         // wave's l-block [w*16, w*16+16)
    const int lr   = lane & 15;
    const int lg   = lane >> 4;

    // A-frags (Em rows = l) direct from global, issued before the barrier so
    // their latency overlaps the DMA drain.
    const __hip_bfloat16* __restrict__ ebase =
        Em + (size_t)m * (B_ * TWOB_) + (w * 16 + lr) * TWOB_;
    bf16x8 af[4];
    #pragma unroll
    for (int ks = 0; ks < 4; ++ks)
        af[ks] = *reinterpret_cast<const bf16x8*>(ebase + ks * 32 + lg * 8);

    __syncthreads();                 // drains vmcnt (DMA + af loads)

    f32x4 acc[4];
    #pragma unroll
    for (int nt = 0; nt < 4; ++nt) acc[nt] = (f32x4){0.f, 0.f, 0.f, 0.f};

    #pragma unroll
    for (int ks = 0; ks < 4; ++ks) {
        #pragma unroll
        for (int nt = 0; nt < 4; ++nt) {
            int row = nt * 16 + lr;              // b-row in As
            int u0  = ks * 8 + lg * 2;           // fp32 16B-unit pair
            f32x4 p0 = *reinterpret_cast<const f32x4*>(As + row * TWOB_ + (((u0    ) ^ lr) << 2));
            f32x4 p1 = *reinterpret_cast<const f32x4*>(As + row * TWOB_ + (((u0 + 1) ^ lr) << 2));
            bf16x8 bf;
            bf[0] = f2bf(p0[0]); bf[1] = f2bf(p0[1]); bf[2] = f2bf(p0[2]); bf[3] = f2bf(p0[3]);
            bf[4] = f2bf(p1[0]); bf[5] = f2bf(p1[1]); bf[6] = f2bf(p1[2]); bf[7] = f2bf(p1[3]);
            acc[nt] = __builtin_amdgcn_mfma_f32_16x16x32_bf16(af[ks], bf, acc[nt], 0, 0, 0);
        }
    }

    #pragma unroll
    for (int nt = 0; nt < 4; ++nt) {
        int b = b0 + nt * 16 + lr;
        float4 v;
        v.x = acc[nt][0]; v.y = acc[nt][1]; v.z = acc[nt][2]; v.w = acc[nt][3];
        *reinterpret_cast<float4*>(out + ((size_t)b * M_ + m) * B_ + w * 16 + lg * 4) = v;
    }
}

extern "C" void kernel_launch(void* const* d_in, const int* in_sizes, int n_in,
                              void* d_out, int out_size, void* d_ws, size_t ws_size,
                              hipStream_t stream) {
    const float* psiHat = (const float*)d_in[0];
    const float* Cm     = (const float*)d_in[1];
    const float* XFc    = (const float*)d_in[2];
    const float* XFs    = (const float*)d_in[3];
    const float* Dval   = (const float*)d_in[4];
    const int*   Drow   = (const int*)d_in[5];
    const int*   Dcol   = (const int*)d_in[6];
    const int nnz = in_sizes[4];

    __hip_bfloat16* Em = (__hip_bfloat16*)d_ws;   // 127*64*128*2 = 2,080,768 B

    build_Em<<<dim3(M_), dim3(256), 0, stream>>>(Cm, XFc, XFs, Dval, Drow, Dcol, nnz, Em);
    fdlt_gemm<<<dim3(1024), dim3(256), 0, stream>>>(psiHat, Em, (float*)d_out);
}

// Round 9
// 26.422 us; speedup vs baseline: 6.8664x; 1.0086x over previous
//
#include <hip/hip_runtime.h>
#include <hip/hip_bf16.h>

// FDLT: out[b,m,l] = sum_k psiHat[b,m,k] * Em[m][k][l]   (fp32 in/out)
//   Em[m][k][l] = Cm[m] * sum_{n=0..63} XF_sel(m)[k][n] * Dm[m][l][n]
// B=64, M=127, 2B=128, BATCH=512. Em bf16 [m][l][k] in d_ws.
// Round 9: gemm As tile staged as BF16 via reg-staging (cvt once, LDS 16KB,
// 8 blocks/CU) -- R8's fp32 As had 4x-redundant ds_read+cvt in compute and
// only ~4 blocks/CU of latency hiding. build_Em unchanged from R8.

#define B_     64
#define M_     127
#define TWOB_  128

using bf16x8 = __attribute__((ext_vector_type(8))) short;  // 8 bf16 (4 VGPR)
using f32x4  = __attribute__((ext_vector_type(4))) float;

__device__ inline short f2bf(float x) {
    __hip_bfloat16 h = __float2bfloat16(x);
    return *reinterpret_cast<short*>(&h);
}

// ---------------------------------------------------------------------------
// Kernel 1 (UNCHANGED from R8): per m,
//   Em[64l x 128k] = bf16( cm * Dm[64l x 64n] @ XF[128k x 64n]^T )  via MFMA.
// 127 blocks x 256 thr. Dmb bf16 LDS tile, 16B-unit swizzle u ^= (l&7).
// ---------------------------------------------------------------------------
__global__ __launch_bounds__(256) void build_Em(
    const float* __restrict__ Cm,
    const float* __restrict__ XFc,
    const float* __restrict__ XFs,
    const float* __restrict__ Dval,
    const int*   __restrict__ Drow,
    const int*   __restrict__ Dcol,
    int nnz,
    __hip_bfloat16* __restrict__ Em)
{
    __shared__ short Dmb[B_ * B_];   // 8 KB
    const int m = blockIdx.x;
    const int t = threadIdx.x;

    {
        uint4 z = make_uint4(0, 0, 0, 0);
        uint4* p = reinterpret_cast<uint4*>(Dmb);
        p[t] = z;
        p[t + 256] = z;
    }
    int lo, hi;
    {
        int target = m * B_;
        int a = 0, b = nnz;
        while (a < b) { int mid = (a + b) >> 1; if (Drow[mid] < target) a = mid + 1; else b = mid; }
        lo = a;
        target = (m + 1) * B_;
        b = nnz;
        while (a < b) { int mid = (a + b) >> 1; if (Drow[mid] < target) a = mid + 1; else b = mid; }
        hi = a;
    }
    __syncthreads();
    for (int i = lo + t; i < hi; i += 256) {
        int l = Drow[i] - m * B_;
        int n = Dcol[i] - m * TWOB_;
        int u = n >> 3;
        Dmb[l * B_ + (((u ^ (l & 7)) << 3) | (n & 7))] = f2bf(Dval[i]);
    }
    __syncthreads();

    const float* __restrict__ XF = (m & 1) ? XFc : XFs;
    const float cm = Cm[m];
    const int w    = t >> 6;
    const int lane = t & 63;
    const int lr   = lane & 15;
    const int lg   = lane >> 4;

    f32x4 acc[2][4];
    #pragma unroll
    for (int at = 0; at < 2; ++at)
        #pragma unroll
        for (int nt = 0; nt < 4; ++nt) acc[at][nt] = (f32x4){0.f, 0.f, 0.f, 0.f};

    #pragma unroll
    for (int ks = 0; ks < 2; ++ks) {
        bf16x8 af[2];
        #pragma unroll
        for (int at = 0; at < 2; ++at) {
            const float* ap = XF + (size_t)(w * 32 + at * 16 + lr) * TWOB_ + ks * 32 + lg * 8;
            f32x4 p0 = *reinterpret_cast<const f32x4*>(ap);
            f32x4 p1 = *reinterpret_cast<const f32x4*>(ap + 4);
            af[at][0] = f2bf(p0[0]); af[at][1] = f2bf(p0[1]);
            af[at][2] = f2bf(p0[2]); af[at][3] = f2bf(p0[3]);
            af[at][4] = f2bf(p1[0]); af[at][5] = f2bf(p1[1]);
            af[at][6] = f2bf(p1[2]); af[at][7] = f2bf(p1[3]);
        }
        #pragma unroll
        for (int nt = 0; nt < 4; ++nt) {
            int l = nt * 16 + lr;
            int g = ks * 4 + lg;
            bf16x8 bf = *reinterpret_cast<const bf16x8*>(Dmb + l * B_ + ((g ^ (l & 7)) << 3));
            #pragma unroll
            for (int at = 0; at < 2; ++at)
                acc[at][nt] = __builtin_amdgcn_mfma_f32_16x16x32_bf16(af[at], bf, acc[at][nt], 0, 0, 0);
        }
    }

    #pragma unroll
    for (int at = 0; at < 2; ++at) {
        #pragma unroll
        for (int nt = 0; nt < 4; ++nt) {
            int l  = nt * 16 + lr;
            int k0 = w * 32 + at * 16 + lg * 4;
            unsigned short h0 = (unsigned short)f2bf(cm * acc[at][nt][0]);
            unsigned short h1 = (unsigned short)f2bf(cm * acc[at][nt][1]);
            unsigned short h2 = (unsigned short)f2bf(cm * acc[at][nt][2]);
            unsigned short h3 = (unsigned short)f2bf(cm * acc[at][nt][3]);
            uint2 pack;
            pack.x = (unsigned)h0 | ((unsigned)h1 << 16);
            pack.y = (unsigned)h2 | ((unsigned)h3 << 16);
            *reinterpret_cast<uint2*>(Em + (size_t)(m * B_ + l) * TWOB_ + k0) = pack;
        }
    }
}

// ---------------------------------------------------------------------------
// Kernel 2: per (m, batch-tile): out[64l x 64b] = E[64l x 128k] @ A[128k x 64b]
// 1024 blocks, XCD mapping m = (bid&7) + 8*((bid>>3)&15), tile = bid>>7.
// As staged BF16 by reg-staging: per thread 4 units (2x float4 load -> 8 cvt
// -> 1 ds_write_b128), swizzle on the WRITE side (u ^= row&15). 16 KB LDS ->
// 8 blocks/CU (launch_bounds(256,8)). Inner loop/wave: 16 ds_read_b128 +
// 16 MFMA, zero cvt. af (Em rows, 16B) direct from L2-hot global.
// D: col=lane&15=b, row=lg*4+r=l -> float4 store of 4 consecutive l.
// ---------------------------------------------------------------------------
__global__ __launch_bounds__(256, 8) void fdlt_gemm(
    const float* __restrict__ psiHat,
    const __hip_bfloat16* __restrict__ Em,
    float* __restrict__ out)
{
    __shared__ short As[64 * 128];   // bf16 [b][k], 16 KB, 16B-unit swizzled

    const int bid  = blockIdx.x;
    const int xcd  = bid & 7;
    const int rest = bid >> 3;
    const int m    = xcd + ((rest & 15) << 3);
    const int tile = rest >> 4;
    if (m >= M_) return;             // 8 guard blocks, uniform exit
    const int b0 = tile * 64;
    const int t  = threadIdx.x;

    const int lane = t & 63;
    const int w    = t >> 6;         // wave's l-block [w*16, w*16+16)
    const int lr   = lane & 15;
    const int lg   = lane >> 4;

    // A-frags (Em rows = l) direct from global L2 (16 KB per m, XCD-local).
    const __hip_bfloat16* __restrict__ ebase =
        Em + (size_t)m * (B_ * TWOB_) + (w * 16 + lr) * TWOB_;
    bf16x8 af[4];
    #pragma unroll
    for (int ks = 0; ks < 4; ++ks)
        af[ks] = *reinterpret_cast<const bf16x8*>(ebase + ks * 32 + lg * 8);

    // stage As: 1024 bf16 16B-units, 4 per thread; coalesced 32B/lane reads.
    #pragma unroll
    for (int j = 0; j < 4; ++j) {
        int unit = t + j * 256;
        int row  = unit >> 4;        // b-row
        int u    = unit & 15;        // 16B unit within row
        const float* src = psiHat + ((size_t)(b0 + row) * M_ + m) * TWOB_ + u * 8;
        f32x4 p0 = *reinterpret_cast<const f32x4*>(src);
        f32x4 p1 = *reinterpret_cast<const f32x4*>(src + 4);
        bf16x8 s;
        s[0] = f2bf(p0[0]); s[1] = f2bf(p0[1]); s[2] = f2bf(p0[2]); s[3] = f2bf(p0[3]);
        s[4] = f2bf(p1[0]); s[5] = f2bf(p1[1]); s[6] = f2bf(p1[2]); s[7] = f2bf(p1[3]);
        *reinterpret_cast<bf16x8*>(As + row * TWOB_ + ((u ^ (row & 15)) << 3)) = s;
    }
    __syncthreads();

    f32x4 acc[4];
    #pragma unroll
    for (int nt = 0; nt < 4; ++nt) acc[nt] = (f32x4){0.f, 0.f, 0.f, 0.f};

    #pragma unroll
    for (int ks = 0; ks < 4; ++ks) {
        #pragma unroll
        for (int nt = 0; nt < 4; ++nt) {
            int row = nt * 16 + lr;                  // b-row; row&15 == lr
            int g   = ks * 4 + lg;
            bf16x8 bf = *reinterpret_cast<const bf16x8*>(As + row * TWOB_ + ((g ^ lr) << 3));
            acc[nt] = __builtin_amdgcn_mfma_f32_16x16x32_bf16(af[ks], bf, acc[nt], 0, 0, 0);
        }
    }

    #pragma unroll
    for (int nt = 0; nt < 4; ++nt) {
        int b = b0 + nt * 16 + lr;
        float4 v;
        v.x = acc[nt][0]; v.y = acc[nt][1]; v.z = acc[nt][2]; v.w = acc[nt][3];
        *reinterpret_cast<float4*>(out + ((size_t)b * M_ + m) * B_ + w * 16 + lg * 4) = v;
    }
}

extern "C" void kernel_launch(void* const* d_in, const int* in_sizes, int n_in,
                              void* d_out, int out_size, void* d_ws, size_t ws_size,
                              hipStream_t stream) {
    const float* psiHat = (const float*)d_in[0];
    const float* Cm     = (const float*)d_in[1];
    const float* XFc    = (const float*)d_in[2];
    const float* XFs    = (const float*)d_in[3];
    const float* Dval   = (const float*)d_in[4];
    const int*   Drow   = (const int*)d_in[5];
    const int*   Dcol   = (const int*)d_in[6];
    const int nnz = in_sizes[4];

    __hip_bfloat16* Em = (__hip_bfloat16*)d_ws;   // 127*64*128*2 = 2,080,768 B

    build_Em<<<dim3(M_), dim3(256), 0, stream>>>(Cm, XFc, XFs, Dval, Drow, Dcol, nnz, Em);
    fdlt_gemm<<<dim3(1024), dim3(256), 0, stream>>>(psiHat, Em, (float*)d_out);
}

// Round 10
// 24.911 us; speedup vs baseline: 7.2829x; 1.0607x over previous
//
#include <hip/hip_runtime.h>
#include <hip/hip_bf16.h>

// FDLT: out[b,m,l] = sum_k psiHat[b,m,k] * Em[m][k][l]   (fp32 in/out)
//   Em[m][k][l] = Cm[m] * sum_{n=0..63} XF_sel(m)[k][n] * Dm[m][l][n]
// B=64, M=127, 2B=128, BATCH=512. Em bf16 [m][l][k] in d_ws.
// Round 10: build-side latency attack, gemm EXACTLY R9.
//  k0 row_start_k: CSR row pointers from sorted Drow (kills build's cold
//     26-deep bsearch pointer-chase; pre-warms COO in L2).
//  k1 build_Em: 254 blocks (full chip), scatter via 9 unrolled predicated
//     rounds (all loads issued before any use -> single latency).
//  k2 fdlt_gemm: unchanged R9 (bf16 As reg-staged, 16KB LDS, 8 blk/CU).

#define B_     64
#define M_     127
#define TWOB_  128
#define NROWS  (M_ * B_)   // 8128

using bf16x8 = __attribute__((ext_vector_type(8))) short;  // 8 bf16 (4 VGPR)
using f32x4  = __attribute__((ext_vector_type(4))) float;

__device__ inline short f2bf(float x) {
    __hip_bfloat16 h = __float2bfloat16(x);
    return *reinterpret_cast<short*>(&h);
}

// ---------------------------------------------------------------------------
// Kernel 0: row_start[r] = first i with Drow[i] >= r, r in [0, 8128].
// Coalesced streaming read of Drow; per-thread short fill loop over the gap
// to the previous entry (gaps only at empty high-|m| rows, <= 64).
// ---------------------------------------------------------------------------
__global__ __launch_bounds__(256) void row_start_k(
    const int* __restrict__ Drow, int nnz, int* __restrict__ row_start)
{
    int i = blockIdx.x * 256 + threadIdx.x;
    if (i >= nnz) return;
    int cur  = Drow[i];
    int prev = (i == 0) ? -1 : Drow[i - 1];
    for (int r = prev + 1; r <= cur; ++r) row_start[r] = i;
    if (i == nnz - 1)
        for (int r = cur + 1; r <= NROWS; ++r) row_start[r] = nnz;
}

// ---------------------------------------------------------------------------
// Kernel 1: per m, Em[64l x 128k] = bf16( cm * Dm[64l x 64n] @ XF[128k x 64n]^T )
// Grid (2, 127) x 256 thr: block h owns k-half [h*64, h*64+64); wave w owns
// k-tile [h*64+w*16, +16). Dmb bf16 LDS tile (8KB), unit swizzle u ^= (l&7).
// Scatter: segment [lo,hi) from row_start (no bsearch); <=2080 entries ->
// 9 rounds fully unrolled, loads all issued first (one latency, not nine).
// ---------------------------------------------------------------------------
__global__ __launch_bounds__(256) void build_Em(
    const float* __restrict__ Cm,
    const float* __restrict__ XFc,
    const float* __restrict__ XFs,
    const float* __restrict__ Dval,
    const int*   __restrict__ Drow,
    const int*   __restrict__ Dcol,
    const int*   __restrict__ row_start,
    int nnz,
    __hip_bfloat16* __restrict__ Em)
{
    __shared__ short Dmb[B_ * B_];   // 8 KB
    const int m = blockIdx.y;
    const int h = blockIdx.x;        // k-half
    const int t = threadIdx.x;

    {   // zero 8KB
        uint4 z = make_uint4(0, 0, 0, 0);
        uint4* p = reinterpret_cast<uint4*>(Dmb);
        p[t] = z;
        p[t + 256] = z;
    }
    const int lo = row_start[m * B_];
    const int hi = row_start[(m + 1) * B_];

    // issue all segment loads up-front (clamped), then predicated scatter
    int   rr[9], cc[9];
    float vv[9];
    bool  ok[9];
    #pragma unroll
    for (int j = 0; j < 9; ++j) {
        int i  = lo + t + j * 256;
        ok[j]  = (i < hi);
        int ic = i < nnz ? i : (nnz - 1);
        rr[j] = Drow[ic];
        cc[j] = Dcol[ic];
        vv[j] = Dval[ic];
    }
    __syncthreads();
    #pragma unroll
    for (int j = 0; j < 9; ++j) {
        if (ok[j]) {
            int l = rr[j] - m * B_;
            int n = cc[j] - m * TWOB_;
            int u = n >> 3;
            Dmb[l * B_ + (((u ^ (l & 7)) << 3) | (n & 7))] = f2bf(vv[j]);
        }
    }
    __syncthreads();

    const float* __restrict__ XF = (m & 1) ? XFc : XFs;
    const float cm = Cm[m];
    const int w    = t >> 6;
    const int lane = t & 63;
    const int lr   = lane & 15;
    const int lg   = lane >> 4;
    const int k0   = h * 64 + w * 16;          // this wave's k-tile base

    f32x4 acc[4];
    #pragma unroll
    for (int nt = 0; nt < 4; ++nt) acc[nt] = (f32x4){0.f, 0.f, 0.f, 0.f};

    #pragma unroll
    for (int ks = 0; ks < 2; ++ks) {           // n-halves of 32
        const float* ap = XF + (size_t)(k0 + lr) * TWOB_ + ks * 32 + lg * 8;
        f32x4 p0 = *reinterpret_cast<const f32x4*>(ap);
        f32x4 p1 = *reinterpret_cast<const f32x4*>(ap + 4);
        bf16x8 af;
        af[0] = f2bf(p0[0]); af[1] = f2bf(p0[1]); af[2] = f2bf(p0[2]); af[3] = f2bf(p0[3]);
        af[4] = f2bf(p1[0]); af[5] = f2bf(p1[1]); af[6] = f2bf(p1[2]); af[7] = f2bf(p1[3]);
        #pragma unroll
        for (int nt = 0; nt < 4; ++nt) {       // B: Dmb col l = nt*16+lr
            int l = nt * 16 + lr;
            int g = ks * 4 + lg;
            bf16x8 bfr = *reinterpret_cast<const bf16x8*>(Dmb + l * B_ + ((g ^ (l & 7)) << 3));
            acc[nt] = __builtin_amdgcn_mfma_f32_16x16x32_bf16(af, bfr, acc[nt], 0, 0, 0);
        }
    }

    // D: col = lr -> l, row = lg*4+r -> k within tile
    #pragma unroll
    for (int nt = 0; nt < 4; ++nt) {
        int l  = nt * 16 + lr;
        int kk = k0 + lg * 4;
        unsigned short h0 = (unsigned short)f2bf(cm * acc[nt][0]);
        unsigned short h1 = (unsigned short)f2bf(cm * acc[nt][1]);
        unsigned short h2 = (unsigned short)f2bf(cm * acc[nt][2]);
        unsigned short h3 = (unsigned short)f2bf(cm * acc[nt][3]);
        uint2 pack;
        pack.x = (unsigned)h0 | ((unsigned)h1 << 16);
        pack.y = (unsigned)h2 | ((unsigned)h3 << 16);
        *reinterpret_cast<uint2*>(Em + (size_t)(m * B_ + l) * TWOB_ + kk) = pack;
    }
}

// ---------------------------------------------------------------------------
// Kernel 2 (UNCHANGED R9): per (m, tile): out[64l x 64b] = E @ A via MFMA.
// ---------------------------------------------------------------------------
__global__ __launch_bounds__(256, 8) void fdlt_gemm(
    const float* __restrict__ psiHat,
    const __hip_bfloat16* __restrict__ Em,
    float* __restrict__ out)
{
    __shared__ short As[64 * 128];   // bf16 [b][k], 16 KB, 16B-unit swizzled

    const int bid  = blockIdx.x;
    const int xcd  = bid & 7;
    const int rest = bid >> 3;
    const int m    = xcd + ((rest & 15) << 3);
    const int tile = rest >> 4;
    if (m >= M_) return;
    const int b0 = tile * 64;
    const int t  = threadIdx.x;

    const int lane = t & 63;
    const int w    = t >> 6;
    const int lr   = lane & 15;
    const int lg   = lane >> 4;

    const __hip_bfloat16* __restrict__ ebase =
        Em + (size_t)m * (B_ * TWOB_) + (w * 16 + lr) * TWOB_;
    bf16x8 af[4];
    #pragma unroll
    for (int ks = 0; ks < 4; ++ks)
        af[ks] = *reinterpret_cast<const bf16x8*>(ebase + ks * 32 + lg * 8);

    #pragma unroll
    for (int j = 0; j < 4; ++j) {
        int unit = t + j * 256;
        int row  = unit >> 4;
        int u    = unit & 15;
        const float* src = psiHat + ((size_t)(b0 + row) * M_ + m) * TWOB_ + u * 8;
        f32x4 p0 = *reinterpret_cast<const f32x4*>(src);
        f32x4 p1 = *reinterpret_cast<const f32x4*>(src + 4);
        bf16x8 s;
        s[0] = f2bf(p0[0]); s[1] = f2bf(p0[1]); s[2] = f2bf(p0[2]); s[3] = f2bf(p0[3]);
        s[4] = f2bf(p1[0]); s[5] = f2bf(p1[1]); s[6] = f2bf(p1[2]); s[7] = f2bf(p1[3]);
        *reinterpret_cast<bf16x8*>(As + row * TWOB_ + ((u ^ (row & 15)) << 3)) = s;
    }
    __syncthreads();

    f32x4 acc[4];
    #pragma unroll
    for (int nt = 0; nt < 4; ++nt) acc[nt] = (f32x4){0.f, 0.f, 0.f, 0.f};

    #pragma unroll
    for (int ks = 0; ks < 4; ++ks) {
        #pragma unroll
        for (int nt = 0; nt < 4; ++nt) {
            int row = nt * 16 + lr;
            int g   = ks * 4 + lg;
            bf16x8 bfr = *reinterpret_cast<const bf16x8*>(As + row * TWOB_ + ((g ^ lr) << 3));
            acc[nt] = __builtin_amdgcn_mfma_f32_16x16x32_bf16(af[ks], bfr, acc[nt], 0, 0, 0);
        }
    }

    #pragma unroll
    for (int nt = 0; nt < 4; ++nt) {
        int b = b0 + nt * 16 + lr;
        float4 v;
        v.x = acc[nt][0]; v.y = acc[nt][1]; v.z = acc[nt][2]; v.w = acc[nt][3];
        *reinterpret_cast<float4*>(out + ((size_t)b * M_ + m) * B_ + w * 16 + lg * 4) = v;
    }
}

extern "C" void kernel_launch(void* const* d_in, const int* in_sizes, int n_in,
                              void* d_out, int out_size, void* d_ws, size_t ws_size,
                              hipStream_t stream) {
    const float* psiHat = (const float*)d_in[0];
    const float* Cm     = (const float*)d_in[1];
    const float* XFc    = (const float*)d_in[2];
    const float* XFs    = (const float*)d_in[3];
    const float* Dval   = (const float*)d_in[4];
    const int*   Drow   = (const int*)d_in[5];
    const int*   Dcol   = (const int*)d_in[6];
    const int nnz = in_sizes[4];

    // ws layout: [0, 2,080,768) Em bf16; then row_start[8129] int.
    __hip_bfloat16* Em = (__hip_bfloat16*)d_ws;
    int* row_start = (int*)((char*)d_ws + (size_t)M_ * B_ * TWOB_ * sizeof(__hip_bfloat16));

    row_start_k<<<dim3((nnz + 255) / 256), dim3(256), 0, stream>>>(Drow, nnz, row_start);
    build_Em<<<dim3(2, M_), dim3(256), 0, stream>>>(Cm, XFc, XFs, Dval, Drow, Dcol,
                                                    row_start, nnz, Em);
    fdlt_gemm<<<dim3(1024), dim3(256), 0, stream>>>(psiHat, Em, (float*)d_out);
}

// Round 11
// 21.861 us; speedup vs baseline: 8.2990x; 1.1395x over previous
//
#include <hip/hip_runtime.h>
#include <hip/hip_bf16.h>

// FDLT fused single-kernel (round 11).
// out[b,m,l] = sum_k psiHat[b,m,k] * Em[m][k][l],
//   Em[m][k][l] = Cm[m] * sum_{n<64} XF_sel(m)[k][n] * Dm[m][l][n]
// Per block (1024 = 8 xcd x 16 m x 8 batch-tiles):
//   ph0: issue psiHat float4 loads -> regs (T14 split: write-late)
//        zero Dmb; bsearch COO row segment; issue scatter loads
//   ph1: scatter Dm -> Dmb LDS (bf16, u^(l&7) swizzle)
//   ph2: build EmL[64l][128k] in LDS via 16 MFMA/wave vs L2-hot XF
//   ph3: cvt+ds_write As (REUSES Dmb region; psiHat loads from ph0)
//   ph4: main 16 MFMA/wave: af from EmL, bfr from As; float4 stores.
// LDS: EmL 16KB + (Dmb 8KB | As 16KB shared) = 32KB. No global Em, 1 launch.

#define B_     64
#define M_     127
#define TWOB_  128

using bf16x8 = __attribute__((ext_vector_type(8))) short;  // 8 bf16 (4 VGPR)
using f32x4  = __attribute__((ext_vector_type(4))) float;

__device__ inline short f2bf(float x) {
    __hip_bfloat16 h = __float2bfloat16(x);
    return *reinterpret_cast<short*>(&h);
}

__global__ __launch_bounds__(256, 4) void fdlt_fused(
    const float* __restrict__ psiHat,
    const float* __restrict__ Cm,
    const float* __restrict__ XFc,
    const float* __restrict__ XFs,
    const float* __restrict__ Dval,
    const int*   __restrict__ Drow,
    const int*   __restrict__ Dcol,
    int nnz,
    float* __restrict__ out)
{
    __shared__ short EmL[B_ * TWOB_];   // 16 KB, persists ph2->ph4
    __shared__ short ShB[B_ * TWOB_];   // 16 KB: ph1-2 Dmb (first 8KB), ph3+ As
    short* Dmb = ShB;

    const int bid  = blockIdx.x;
    const int xcd  = bid & 7;
    const int rest = bid >> 3;
    const int m    = xcd + ((rest & 15) << 3);   // 16 m's per XCD (L2 locality)
    const int tile = rest >> 4;
    if (m >= M_) return;                         // 8 guard blocks, uniform exit
    const int b0 = tile * 64;
    const int t  = threadIdx.x;

    const int lane = t & 63;
    const int w    = t >> 6;
    const int lr   = lane & 15;
    const int lg   = lane >> 4;

    // ---- ph0a: issue psiHat loads early (consumed in ph3)
    f32x4 pre[8];
    #pragma unroll
    for (int j = 0; j < 4; ++j) {
        int unit = t + j * 256;                  // 1024 16B-units of As
        int row  = unit >> 4;                    // b-row
        int u    = unit & 15;
        const float* src = psiHat + ((size_t)(b0 + row) * M_ + m) * TWOB_ + u * 8;
        pre[2 * j]     = *reinterpret_cast<const f32x4*>(src);
        pre[2 * j + 1] = *reinterpret_cast<const f32x4*>(src + 4);
    }

    // ---- ph0b: zero Dmb (512 uint4)
    {
        uint4 z = make_uint4(0, 0, 0, 0);
        uint4* p = reinterpret_cast<uint4*>(Dmb);
        p[t] = z;
        p[t + 256] = z;
    }

    // ---- ph0c: COO segment for rows [m*64, (m+1)*64) + issue scatter loads
    int lo, hi;
    {
        int target = m * B_;
        int a = 0, b = nnz;
        while (a < b) { int mid = (a + b) >> 1; if (Drow[mid] < target) a = mid + 1; else b = mid; }
        lo = a;
        target = (m + 1) * B_;
        b = nnz;
        while (a < b) { int mid = (a + b) >> 1; if (Drow[mid] < target) a = mid + 1; else b = mid; }
        hi = a;
    }
    int   rr[9], cc[9];
    float vv[9];
    bool  ok[9];
    #pragma unroll
    for (int j = 0; j < 9; ++j) {                // max segment 2080 <= 9*256
        int i  = lo + t + j * 256;
        ok[j]  = (i < hi);
        int ic = i < nnz ? i : (nnz - 1);
        rr[j] = Drow[ic];
        cc[j] = Dcol[ic];
        vv[j] = Dval[ic];
    }
    __syncthreads();                             // zeroing visible

    // ---- ph1: scatter into Dmb, swizzle u ^= (l&7) (row = 64 shorts = 128B)
    #pragma unroll
    for (int j = 0; j < 9; ++j) {
        if (ok[j]) {
            int l = rr[j] - m * B_;
            int n = cc[j] - m * TWOB_;
            int u = n >> 3;
            Dmb[l * B_ + (((u ^ (l & 7)) << 3) | (n & 7))] = f2bf(vv[j]);
        }
    }
    __syncthreads();

    // ---- ph2: build EmL = cm * Dm[64x64] @ XF[128x64]^T via MFMA.
    // Wave w owns k-tiles {2w, 2w+1} x all 4 l-tiles (8 C-tiles, 16 MFMA).
    const float* __restrict__ XF = (m & 1) ? XFc : XFs;
    const float cm = Cm[m];

    f32x4 bacc[2][4];
    #pragma unroll
    for (int kt2 = 0; kt2 < 2; ++kt2)
        #pragma unroll
        for (int lt = 0; lt < 4; ++lt) bacc[kt2][lt] = (f32x4){0.f, 0.f, 0.f, 0.f};

    #pragma unroll
    for (int ks = 0; ks < 2; ++ks) {             // n-halves of 32
        bf16x8 af[2];
        #pragma unroll
        for (int kt2 = 0; kt2 < 2; ++kt2) {      // A: XF row k = (2w+kt2)*16+lr
            const float* ap = XF + (size_t)((w * 2 + kt2) * 16 + lr) * TWOB_ + ks * 32 + lg * 8;
            f32x4 p0 = *reinterpret_cast<const f32x4*>(ap);
            f32x4 p1 = *reinterpret_cast<const f32x4*>(ap + 4);
            af[kt2][0] = f2bf(p0[0]); af[kt2][1] = f2bf(p0[1]);
            af[kt2][2] = f2bf(p0[2]); af[kt2][3] = f2bf(p0[3]);
            af[kt2][4] = f2bf(p1[0]); af[kt2][5] = f2bf(p1[1]);
            af[kt2][6] = f2bf(p1[2]); af[kt2][7] = f2bf(p1[3]);
        }
        #pragma unroll
        for (int lt = 0; lt < 4; ++lt) {         // B: Dmb col l = lt*16+lr
            int l = lt * 16 + lr;
            int g = ks * 4 + lg;
            bf16x8 bfr = *reinterpret_cast<const bf16x8*>(Dmb + l * B_ + ((g ^ (l & 7)) << 3));
            bacc[0][lt] = __builtin_amdgcn_mfma_f32_16x16x32_bf16(af[0], bfr, bacc[0][lt], 0, 0, 0);
            bacc[1][lt] = __builtin_amdgcn_mfma_f32_16x16x32_bf16(af[1], bfr, bacc[1][lt], 0, 0, 0);
        }
    }
    // write EmL rows l, unit swizzle u ^= (l&15) (row = 128 shorts = 16 units)
    // lane holds l = lt*16+lr (D col), k = (2w+kt2)*16 + lg*4 + r (D row)
    #pragma unroll
    for (int kt2 = 0; kt2 < 2; ++kt2) {
        #pragma unroll
        for (int lt = 0; lt < 4; ++lt) {
            int l  = lt * 16 + lr;
            int k0 = (w * 2 + kt2) * 16 + lg * 4;
            unsigned short h0 = (unsigned short)f2bf(cm * bacc[kt2][lt][0]);
            unsigned short h1 = (unsigned short)f2bf(cm * bacc[kt2][lt][1]);
            unsigned short h2 = (unsigned short)f2bf(cm * bacc[kt2][lt][2]);
            unsigned short h3 = (unsigned short)f2bf(cm * bacc[kt2][lt][3]);
            uint2 pack;
            pack.x = (unsigned)h0 | ((unsigned)h1 << 16);
            pack.y = (unsigned)h2 | ((unsigned)h3 << 16);
            int u    = k0 >> 3;                  // 16B unit
            int half = (k0 >> 2) & 1;            // 8B half within unit
            *reinterpret_cast<uint2*>(EmL + l * TWOB_ + ((u ^ (l & 15)) << 3) + (half << 2)) = pack;
        }
    }
    __syncthreads();                             // Dmb consumed; EmL visible

    // ---- ph3: As ds_write from ph0 regs (overwrites Dmb region)
    #pragma unroll
    for (int j = 0; j < 4; ++j) {
        int unit = t + j * 256;
        int row  = unit >> 4;
        int u    = unit & 15;
        bf16x8 s;
        s[0] = f2bf(pre[2*j][0]); s[1] = f2bf(pre[2*j][1]);
        s[2] = f2bf(pre[2*j][2]); s[3] = f2bf(pre[2*j][3]);
        s[4] = f2bf(pre[2*j+1][0]); s[5] = f2bf(pre[2*j+1][1]);
        s[6] = f2bf(pre[2*j+1][2]); s[7] = f2bf(pre[2*j+1][3]);
        *reinterpret_cast<bf16x8*>(ShB + row * TWOB_ + ((u ^ (row & 15)) << 3)) = s;
    }
    __syncthreads();

    // ---- ph4: out[64l x 64b] = EmL^T-frags @ As. Wave w: l in [w*16, +16).
    f32x4 acc[4];
    #pragma unroll
    for (int nt = 0; nt < 4; ++nt) acc[nt] = (f32x4){0.f, 0.f, 0.f, 0.f};

    #pragma unroll
    for (int ks = 0; ks < 4; ++ks) {
        int l  = w * 16 + lr;                    // l&15 == lr
        int g2 = ks * 4 + lg;
        bf16x8 af = *reinterpret_cast<const bf16x8*>(EmL + l * TWOB_ + ((g2 ^ lr) << 3));
        #pragma unroll
        for (int nt = 0; nt < 4; ++nt) {
            int row = nt * 16 + lr;              // b-row; row&15 == lr
            bf16x8 bfr = *reinterpret_cast<const bf16x8*>(ShB + row * TWOB_ + ((g2 ^ lr) << 3));
            acc[nt] = __builtin_amdgcn_mfma_f32_16x16x32_bf16(af, bfr, acc[nt], 0, 0, 0);
        }
    }

    // D: col=lr -> b, row=lg*4+r -> l: float4 of 4 consecutive l per b
    #pragma unroll
    for (int nt = 0; nt < 4; ++nt) {
        int b = b0 + nt * 16 + lr;
        float4 v;
        v.x = acc[nt][0]; v.y = acc[nt][1]; v.z = acc[nt][2]; v.w = acc[nt][3];
        *reinterpret_cast<float4*>(out + ((size_t)b * M_ + m) * B_ + w * 16 + lg * 4) = v;
    }
}

extern "C" void kernel_launch(void* const* d_in, const int* in_sizes, int n_in,
                              void* d_out, int out_size, void* d_ws, size_t ws_size,
                              hipStream_t stream) {
    const float* psiHat = (const float*)d_in[0];
    const float* Cm     = (const float*)d_in[1];
    const float* XFc    = (const float*)d_in[2];
    const float* XFs    = (const float*)d_in[3];
    const float* Dval   = (const float*)d_in[4];
    const int*   Drow   = (const int*)d_in[5];
    const int*   Dcol   = (const int*)d_in[6];
    const int nnz = in_sizes[4];

    fdlt_fused<<<dim3(1024), dim3(256), 0, stream>>>(
        psiHat, Cm, XFc, XFs, Dval, Drow, Dcol, nnz, (float*)d_out);
}

// Round 12
// 21.495 us; speedup vs baseline: 8.4404x; 1.0170x over previous
//
#include <hip/hip_runtime.h>
#include <hip/hip_bf16.h>

// FDLT fused single-kernel (round 12).
// out[b,m,l] = sum_k psiHat[b,m,k] * Em[m][k][l],
//   Em[m][k][l] = Cm[m] * sum_{n<64} XF_sel(m)[k][n] * Dm[m][l][n]
// vs R11: (1) serial 2x13-load bsearch replaced by wave-parallel 64-ary
// lower_bound (ballot/popc, ~3 dependent loads per bound); (2) As gets its
// own LDS buffer (40KB total) and is written BEFORE barrier1, overlapping
// the scatter-load latency; barriers 4 -> 3.
// Phases: ph0 issue psiHat loads | zero Dmb | wave-lb lo,hi | issue scatter
//         loads | write As;  B1;  ph1 scatter->Dmb;  B2;  ph2 build EmL via
//         MFMA vs L2-hot XF;  B3;  ph3 main MFMA (EmL x As) -> float4 out.

#define B_     64
#define M_     127
#define TWOB_  128

using bf16x8 = __attribute__((ext_vector_type(8))) short;  // 8 bf16 (4 VGPR)
using f32x4  = __attribute__((ext_vector_type(4))) float;

__device__ inline short f2bf(float x) {
    __hip_bfloat16 h = __float2bfloat16(x);
    return *reinterpret_cast<short*>(&h);
}

// lower_bound over sorted arr[0..n): first i with arr[i] >= target.
// Wave-cooperative 64-ary search: result in [a, a+w] (inclusive) invariant;
// each round shrinks w by ~64x with ONE parallel probe load + ballot.
__device__ inline int wave_lb(const int* __restrict__ arr, int n, int target, int lane) {
    int a = 0, w = n;
    while (w > 64) {
        int step = (w + 63) >> 6;
        int off  = lane * step;
        bool inr = (off < w);
        int p    = a + (inr ? off : 0);
        int v    = (inr && p < n) ? arr[p] : 0x7fffffff;
        unsigned long long mask = __ballot(v < target);
        int c = __popcll(mask);
        int a2 = (c > 0) ? (a + (c - 1) * step + 1) : a;
        int U  = (c * step < w) ? (a + c * step) : (a + w);
        a = a2;
        w = U - a2;
        if (w < 0) w = 0;
    }
    bool lt = (lane < w) && (a + lane < n) && (arr[a + lane] < target);
    return a + __popcll(__ballot(lt));
}

__global__ __launch_bounds__(256, 4) void fdlt_fused(
    const float* __restrict__ psiHat,
    const float* __restrict__ Cm,
    const float* __restrict__ XFc,
    const float* __restrict__ XFs,
    const float* __restrict__ Dval,
    const int*   __restrict__ Drow,
    const int*   __restrict__ Dcol,
    int nnz,
    float* __restrict__ out)
{
    __shared__ short EmL[B_ * TWOB_];   // 16 KB, ph2 -> ph3
    __shared__ short As [B_ * TWOB_];   // 16 KB, ph0 -> ph3 (own buffer now)
    __shared__ short Dmb[B_ * B_];      //  8 KB, ph1 -> ph2

    const int bid  = blockIdx.x;
    const int xcd  = bid & 7;
    const int rest = bid >> 3;
    const int m    = xcd + ((rest & 15) << 3);   // 16 m's per XCD (L2 locality)
    const int tile = rest >> 4;
    if (m >= M_) return;                         // 8 guard blocks, uniform exit
    const int b0 = tile * 64;
    const int t  = threadIdx.x;

    const int lane = t & 63;
    const int w    = t >> 6;
    const int lr   = lane & 15;
    const int lg   = lane >> 4;

    // ---- ph0a: issue psiHat loads early (consumed by As write below)
    f32x4 pre[8];
    #pragma unroll
    for (int j = 0; j < 4; ++j) {
        int unit = t + j * 256;                  // 1024 16B-units of As
        int row  = unit >> 4;                    // b-row
        int u    = unit & 15;
        const float* src = psiHat + ((size_t)(b0 + row) * M_ + m) * TWOB_ + u * 8;
        pre[2 * j]     = *reinterpret_cast<const f32x4*>(src);
        pre[2 * j + 1] = *reinterpret_cast<const f32x4*>(src + 4);
    }

    // ---- ph0b: zero Dmb (512 uint4, 2/thread)
    {
        uint4 z = make_uint4(0, 0, 0, 0);
        uint4* p = reinterpret_cast<uint4*>(Dmb);
        p[t] = z;
        p[t + 256] = z;
    }

    // ---- ph0c: COO segment via wave-parallel lower_bound (3 dep loads each)
    const int lo = wave_lb(Drow, nnz, m * B_, lane);
    const int hi = wave_lb(Drow, nnz, (m + 1) * B_, lane);

    // ---- ph0d: issue scatter loads (all up-front, clamped, predicated use)
    int   rr[9], cc[9];
    float vv[9];
    bool  ok[9];
    #pragma unroll
    for (int j = 0; j < 9; ++j) {                // max segment 2304 <= 9*256
        int i  = lo + t + j * 256;
        ok[j]  = (i < hi);
        int ic = i < nnz ? i : (nnz - 1);
        rr[j] = Drow[ic];
        cc[j] = Dcol[ic];
        vv[j] = Dval[ic];
    }

    // ---- ph0e: write As (waits psiHat vmcnt; scatter loads stay in flight)
    #pragma unroll
    for (int j = 0; j < 4; ++j) {
        int unit = t + j * 256;
        int row  = unit >> 4;
        int u    = unit & 15;
        bf16x8 s;
        s[0] = f2bf(pre[2*j][0]); s[1] = f2bf(pre[2*j][1]);
        s[2] = f2bf(pre[2*j][2]); s[3] = f2bf(pre[2*j][3]);
        s[4] = f2bf(pre[2*j+1][0]); s[5] = f2bf(pre[2*j+1][1]);
        s[6] = f2bf(pre[2*j+1][2]); s[7] = f2bf(pre[2*j+1][3]);
        *reinterpret_cast<bf16x8*>(As + row * TWOB_ + ((u ^ (row & 15)) << 3)) = s;
    }
    __syncthreads();                             // B1: Dmb zero visible

    // ---- ph1: scatter into Dmb, swizzle u ^= (l&7) (row = 64 shorts = 128B)
    #pragma unroll
    for (int j = 0; j < 9; ++j) {
        if (ok[j]) {
            int l = rr[j] - m * B_;
            int n = cc[j] - m * TWOB_;
            int u = n >> 3;
            Dmb[l * B_ + (((u ^ (l & 7)) << 3) | (n & 7))] = f2bf(vv[j]);
        }
    }
    __syncthreads();                             // B2: Dmb scattered

    // ---- ph2: build EmL = cm * Dm[64x64] @ XF[128x64]^T via MFMA.
    const float* __restrict__ XF = (m & 1) ? XFc : XFs;
    const float cm = Cm[m];

    f32x4 bacc[2][4];
    #pragma unroll
    for (int kt2 = 0; kt2 < 2; ++kt2)
        #pragma unroll
        for (int lt = 0; lt < 4; ++lt) bacc[kt2][lt] = (f32x4){0.f, 0.f, 0.f, 0.f};

    #pragma unroll
    for (int ks = 0; ks < 2; ++ks) {             // n-halves of 32
        bf16x8 af[2];
        #pragma unroll
        for (int kt2 = 0; kt2 < 2; ++kt2) {      // A: XF row k = (2w+kt2)*16+lr
            const float* ap = XF + (size_t)((w * 2 + kt2) * 16 + lr) * TWOB_ + ks * 32 + lg * 8;
            f32x4 p0 = *reinterpret_cast<const f32x4*>(ap);
            f32x4 p1 = *reinterpret_cast<const f32x4*>(ap + 4);
            af[kt2][0] = f2bf(p0[0]); af[kt2][1] = f2bf(p0[1]);
            af[kt2][2] = f2bf(p0[2]); af[kt2][3] = f2bf(p0[3]);
            af[kt2][4] = f2bf(p1[0]); af[kt2][5] = f2bf(p1[1]);
            af[kt2][6] = f2bf(p1[2]); af[kt2][7] = f2bf(p1[3]);
        }
        #pragma unroll
        for (int lt = 0; lt < 4; ++lt) {         // B: Dmb col l = lt*16+lr
            int l = lt * 16 + lr;
            int g = ks * 4 + lg;
            bf16x8 bfr = *reinterpret_cast<const bf16x8*>(Dmb + l * B_ + ((g ^ (l & 7)) << 3));
            bacc[0][lt] = __builtin_amdgcn_mfma_f32_16x16x32_bf16(af[0], bfr, bacc[0][lt], 0, 0, 0);
            bacc[1][lt] = __builtin_amdgcn_mfma_f32_16x16x32_bf16(af[1], bfr, bacc[1][lt], 0, 0, 0);
        }
    }
    // write EmL rows l, unit swizzle u ^= (l&15); lane: l = lt*16+lr (D col),
    // k = (2w+kt2)*16 + lg*4 + r (D row) -> uint2 (8B half of a 16B unit)
    #pragma unroll
    for (int kt2 = 0; kt2 < 2; ++kt2) {
        #pragma unroll
        for (int lt = 0; lt < 4; ++lt) {
            int l  = lt * 16 + lr;
            int k0 = (w * 2 + kt2) * 16 + lg * 4;
            unsigned short h0 = (unsigned short)f2bf(cm * bacc[kt2][lt][0]);
            unsigned short h1 = (unsigned short)f2bf(cm * bacc[kt2][lt][1]);
            unsigned short h2 = (unsigned short)f2bf(cm * bacc[kt2][lt][2]);
            unsigned short h3 = (unsigned short)f2bf(cm * bacc[kt2][lt][3]);
            uint2 pack;
            pack.x = (unsigned)h0 | ((unsigned)h1 << 16);
            pack.y = (unsigned)h2 | ((unsigned)h3 << 16);
            int u    = k0 >> 3;
            int half = (k0 >> 2) & 1;
            *reinterpret_cast<uint2*>(EmL + l * TWOB_ + ((u ^ (l & 15)) << 3) + (half << 2)) = pack;
        }
    }
    __syncthreads();                             // B3: EmL (and As) ready

    // ---- ph3: out[64l x 64b] = EmL-frags @ As. Wave w: l in [w*16, +16).
    f32x4 acc[4];
    #pragma unroll
    for (int nt = 0; nt < 4; ++nt) acc[nt] = (f32x4){0.f, 0.f, 0.f, 0.f};

    #pragma unroll
    for (int ks = 0; ks < 4; ++ks) {
        int l  = w * 16 + lr;                    // l&15 == lr
        int g2 = ks * 4 + lg;
        bf16x8 af = *reinterpret_cast<const bf16x8*>(EmL + l * TWOB_ + ((g2 ^ lr) << 3));
        #pragma unroll
        for (int nt = 0; nt < 4; ++nt) {
            int row = nt * 16 + lr;              // b-row; row&15 == lr
            bf16x8 bfr = *reinterpret_cast<const bf16x8*>(As + row * TWOB_ + ((g2 ^ lr) << 3));
            acc[nt] = __builtin_amdgcn_mfma_f32_16x16x32_bf16(af, bfr, acc[nt], 0, 0, 0);
        }
    }

    // D: col=lr -> b, row=lg*4+r -> l: float4 of 4 consecutive l per b
    #pragma unroll
    for (int nt = 0; nt < 4; ++nt) {
        int b = b0 + nt * 16 + lr;
        float4 v;
        v.x = acc[nt][0]; v.y = acc[nt][1]; v.z = acc[nt][2]; v.w = acc[nt][3];
        *reinterpret_cast<float4*>(out + ((size_t)b * M_ + m) * B_ + w * 16 + lg * 4) = v;
    }
}

extern "C" void kernel_launch(void* const* d_in, const int* in_sizes, int n_in,
                              void* d_out, int out_size, void* d_ws, size_t ws_size,
                              hipStream_t stream) {
    const float* psiHat = (const float*)d_in[0];
    const float* Cm     = (const float*)d_in[1];
    const float* XFc    = (const float*)d_in[2];
    const float* XFs    = (const float*)d_in[3];
    const float* Dval   = (const float*)d_in[4];
    const int*   Drow   = (const int*)d_in[5];
    const int*   Dcol   = (const int*)d_in[6];
    const int nnz = in_sizes[4];

    fdlt_fused<<<dim3(1024), dim3(256), 0, stream>>>(
        psiHat, Cm, XFc, XFs, Dval, Drow, Dcol, nnz, (float*)d_out);
}